// Round 3
// baseline (569.798 us; speedup 1.0000x reference)
//
#include <hip/hip_runtime.h>

// ---------------- problem constants ----------------
#define NB 32
#define C 128
#define H 56
#define W 56
#define HWSZ (H*W)                 // 3136
#define ELTS (NB*C*HWSZ)           // 12,845,056
#define NHW (NB*HWSZ)              // 100,352 per-channel count
#define HP 59                      // padded rows (h' = 0..58, data at 1..56)
#define SLAB 8192                  // bytes per (n,h') slab: 64 w' * 128 c * 1B (i8)

typedef __attribute__((ext_vector_type(8))) short bf16x8;
typedef __attribute__((ext_vector_type(4))) short short4v;
typedef __attribute__((ext_vector_type(4))) float f32x4;
typedef __attribute__((ext_vector_type(4))) int i32x4;

// ---------------- meta (float offsets) ----------------
#define SLOT_SX 0
#define SLOT_SW1 1
#define SLOT_SW2 2
#define SLOT_SA2 3
#define SUM1 8
#define SSQ1 136
#define MAXE1 264
#define MAXNEG1 392
#define SCALE1 520
#define SHIFT1 648
#define SUM2 776
#define SSQ2 904
#define MAXE2 1032
#define MAXNEG2 1160
#define SCALE2 1288
#define SHIFT2 1416

// ---------------- workspace byte offsets ----------------
#define META_OFF 0ull
#define META_BYTES 8192ull
#define XQ_OFF 8192ull
#define XQ_BYTES ((unsigned long long)NB*HP*SLAB)      // 15,466,496
#define A2Q_OFF (XQ_OFF + XQ_BYTES)
#define Y1_OFF (A2Q_OFF + XQ_BYTES)
#define Y_BYTES ((unsigned long long)ELTS*2ull)        // 25,690,112 (bf16)
#define Y2_OFF (Y1_OFF + Y_BYTES)
#define W1Q_OFF (Y2_OFF + Y_BYTES)
#define WQ_BYTES (9ull*2*128*64)                       // 147,456 (i8, [tap][cc][co][64])
#define W2Q_OFF (W1Q_OFF + WQ_BYTES)
// total ~82.6 MB

__device__ __forceinline__ short f2bf_rne(float f) {       // round-nearest-even
    unsigned u = __float_as_uint(f);
    return (short)((u + 0x7FFFu + ((u >> 16) & 1u)) >> 16);
}
__device__ __forceinline__ float bf2f(short s) {
    return __uint_as_float(((unsigned)(unsigned short)s) << 16);
}
// monotone float->unsigned encoding for atomicMax (handles negatives)
__device__ __forceinline__ unsigned fenc(float f) {
    unsigned u = __float_as_uint(f);
    return (u & 0x80000000u) ? ~u : (u | 0x80000000u);
}
__device__ __forceinline__ float fdec(unsigned e) {
    unsigned u = (e & 0x80000000u) ? (e ^ 0x80000000u) : ~e;
    return __uint_as_float(u);
}

// ---------------- absmax reduction ----------------
__global__ void absmax_kernel(const float* __restrict__ p, int n4, unsigned* __restrict__ slot) {
    __shared__ float red[256];
    float m = 0.f;
    int stride = gridDim.x * blockDim.x;
    for (int i = blockIdx.x * blockDim.x + threadIdx.x; i < n4; i += stride) {
        f32x4 v = ((const f32x4*)p)[i];
        m = fmaxf(m, fmaxf(fmaxf(fabsf(v.x), fabsf(v.y)), fmaxf(fabsf(v.z), fabsf(v.w))));
    }
    red[threadIdx.x] = m;
    __syncthreads();
    for (int s = 128; s > 0; s >>= 1) {
        if (threadIdx.x < s) red[threadIdx.x] = fmaxf(red[threadIdx.x], red[threadIdx.x + s]);
        __syncthreads();
    }
    if (threadIdx.x == 0) atomicMax(slot, __float_as_uint(red[0]));
}

// ---------------- zero the pad regions of xq/a2q (ws re-poisoned each run) ----------------
__global__ void pad_zero_kernel(char* __restrict__ xq, char* __restrict__ a2q) {
    int hp = blockIdx.x;                 // 0..58
    int n = blockIdx.y;                  // 0..31
    char* base = (blockIdx.z ? a2q : xq) + ((size_t)n * HP + hp) * SLAB;
    int t = threadIdx.x;
    if (hp == 0 || hp >= 57) {           // full pad rows: 8192B
        f32x4 z = {0.f, 0.f, 0.f, 0.f};
        *(f32x4*)(base + t * 16) = z;
        *(f32x4*)(base + 4096 + t * 16) = z;
    } else {                             // column pads: w'=0 (128B) and w'=57..63 (896B)
        if (t < 32) *(int*)(base + t * 4) = 0;
        else        *(int*)(base + 7296 + (t - 32) * 4) = 0;
    }
}

// ---------------- weight quant + layout [tap][cc][co][64] i8 ----------------
__global__ void quant_w_kernel(const float* __restrict__ w, const float* __restrict__ meta,
                               int slot, char* __restrict__ wq) {
    int idx = blockIdx.x * 256 + threadIdx.x;   // 0..16383
    int co = idx >> 7, ci = idx & 127;
    float qs = 127.f / (meta[slot] + 1e-12f);
    const float* src = w + ((size_t)(co * 128 + ci)) * 9;
    int cc = ci >> 6, cl = ci & 63;
    #pragma unroll
    for (int tap = 0; tap < 9; ++tap) {
        int q = (int)rintf(src[tap] * qs);
        wq[(((size_t)tap * 2 + cc) * 128 + co) * 64 + cl] = (char)q;
    }
}

// ---------------- quantize x (NCHW fp32) -> pre-swizzled padded NHWC i8 codes ----------------
__global__ void quant_x_kernel(const float* __restrict__ x, const float* __restrict__ meta,
                               char* __restrict__ xq) {
    __shared__ float tile[128][57];
    int h = blockIdx.x, n = blockIdx.y, t = threadIdx.x;
    int ci = t >> 1, seg = (t & 1) * 28;
    const float* row = x + (((size_t)(n * C + ci)) * H + h) * W + seg;
    #pragma unroll
    for (int j = 0; j < 28; j += 4) {
        f32x4 v = *(const f32x4*)(row + j);
        tile[ci][seg + j + 0] = v.x;
        tile[ci][seg + j + 1] = v.y;
        tile[ci][seg + j + 2] = v.z;
        tile[ci][seg + j + 3] = v.w;
    }
    __syncthreads();
    float qs = 127.f / (meta[SLOT_SX] + 1e-12f);
    int w = t & 63, cq = t >> 6;        // cq: 32-channel group
    if (w < 56) {
        char* slab = xq + ((size_t)n * HP + (h + 1)) * SLAB;
        int wp = w + 1;
        #pragma unroll
        for (int c2 = 0; c2 < 2; ++c2) {
            union { char c[16]; i32x4 v; } u;
            #pragma unroll
            for (int j = 0; j < 16; ++j)
                u.c[j] = (char)(int)rintf(tile[cq * 32 + c2 * 16 + j][w] * qs);
            int L = wp * 128 + cq * 32 + c2 * 16;
            *(i32x4*)(slab + (L ^ ((wp & 7) << 4))) = u.v;
        }
    }
}

// ---------------- conv 3x3 implicit-GEMM i8 MFMA, 2 rows/block, tap-major ----------------
// xq: pre-swizzled padded i8 slabs; wq: [tap][cc][co][64]; y: NHWC bf16 (real units)
// Fused epilogue: per-channel sum/sumsq/max(v)/max(-v) -> meta atomics.
__global__ __launch_bounds__(256, 3) void conv_mfma_kernel(
        const char* __restrict__ xq, const char* __restrict__ wq,
        short* __restrict__ y, float* __restrict__ meta,
        int slot_in, int slot_w, int sum_off, int ssq_off, int maxe_off, int maxneg_off) {
    __shared__ __align__(16) char lds[4 * SLAB + 512];   // 4 slabs + OOB slack (wpp<=65)
    const int n = blockIdx.y, h0 = blockIdx.x * 2;       // output rows h0, h0+1
    const int t = threadIdx.x, lane = t & 63;
    const int co0 = (t >> 6) * 32, l15 = lane & 15, lg = lane >> 4;

    // stage padded input rows h0 .. h0+3 (slots 0..3), 2 x 16B loads per slab per thread
    const char* slabbase = xq + ((size_t)n * HP + h0) * SLAB;
    #pragma unroll
    for (int s = 0; s < 4; ++s) {
        #pragma unroll
        for (int i = 0; i < 2; ++i) {
            int off = (i * 256 + t) * 16;
            __builtin_amdgcn_global_load_lds(
                (const __attribute__((address_space(1))) unsigned*)(slabbase + s * SLAB + off),
                (__attribute__((address_space(3))) unsigned*)(lds + s * SLAB + off), 16, 0, 0);
        }
    }

    i32x4 acc[2][4][2] = {};   // [row][fj][cohalf]

    #pragma unroll
    for (int kh = 0; kh < 3; ++kh) {
        if (kh == 0)      { asm volatile("s_waitcnt vmcnt(4)" ::: "memory"); }
        else if (kh == 1) { asm volatile("s_waitcnt vmcnt(2)" ::: "memory"); }
        else              { asm volatile("s_waitcnt vmcnt(0)" ::: "memory"); }
        __builtin_amdgcn_s_barrier();
        #pragma unroll
        for (int kw = 0; kw < 3; ++kw) {
            #pragma unroll
            for (int cc = 0; cc < 2; ++cc) {
                const char* wt = wq + (((kh * 3 + kw) * 2 + cc) << 13);
                i32x4 a0 = *(const i32x4*)(wt + (co0 + l15) * 64 + lg * 16);
                i32x4 a1 = *(const i32x4*)(wt + (co0 + 16 + l15) * 64 + lg * 16);
                #pragma unroll
                for (int r = 0; r < 2; ++r) {
                    const char* Bb = lds + (kh + r) * SLAB;
                    #pragma unroll
                    for (int fj = 0; fj < 4; ++fj) {
                        int wpp = fj * 16 + l15 + kw;
                        int L = (wpp << 7) + (cc << 6) + (lg << 4);
                        i32x4 b = *(const i32x4*)(Bb + (L ^ ((wpp & 7) << 4)));
                        acc[r][fj][0] = __builtin_amdgcn_mfma_i32_16x16x64_i8(a0, b, acc[r][fj][0], 0, 0, 0);
                        acc[r][fj][1] = __builtin_amdgcn_mfma_i32_16x16x64_i8(a1, b, acc[r][fj][1], 0, 0, 0);
                    }
                }
            }
        }
    }

    // epilogue: dequant, stats, bf16 NHWC store (meta loads kept below all asm fences)
    float dq = (meta[slot_in] + 1e-12f) * (meta[slot_w] + 1e-12f) * (1.f / 16129.f);

    float a_sum[8] = {}, a_ssq[8] = {}, a_mx[8], a_mxn[8];
    #pragma unroll
    for (int i = 0; i < 8; ++i) { a_mx[i] = -1e30f; a_mxn[i] = -1e30f; }

    #pragma unroll
    for (int r = 0; r < 2; ++r) {
        short* yrow = y + (((size_t)n * H + (h0 + r)) * W) * C;
        #pragma unroll
        for (int ai = 0; ai < 2; ++ai) {
            #pragma unroll
            for (int fj = 0; fj < 4; ++fj) {
                int wo = fj * 16 + l15;
                if (wo < W) {
                    short4v pk;
                    #pragma unroll
                    for (int q = 0; q < 4; ++q) {
                        float v = (float)acc[r][fj][ai][q] * dq;
                        int si = ai * 4 + q;
                        a_sum[si] += v;
                        a_ssq[si] += v * v;
                        a_mx[si]  = fmaxf(a_mx[si], v);
                        a_mxn[si] = fmaxf(a_mxn[si], -v);
                        pk[q] = f2bf_rne(v);
                    }
                    *(short4v*)(yrow + (size_t)wo * C + co0 + ai * 16 + lg * 4) = pk;
                }
            }
        }
    }

    // cross-l15 reduce (16 lanes share a channel set), then one atomic set per wave
    #pragma unroll
    for (int si = 0; si < 8; ++si) {
        float s1 = a_sum[si], s2 = a_ssq[si], m1 = a_mx[si], m2 = a_mxn[si];
        #pragma unroll
        for (int m = 1; m < 16; m <<= 1) {
            s1 += __shfl_xor(s1, m, 64);
            s2 += __shfl_xor(s2, m, 64);
            m1 = fmaxf(m1, __shfl_xor(m1, m, 64));
            m2 = fmaxf(m2, __shfl_xor(m2, m, 64));
        }
        if (l15 == 0) {
            int cch = co0 + (si >> 2) * 16 + lg * 4 + (si & 3);
            atomicAdd(&meta[sum_off + cch], s1);
            atomicAdd(&meta[ssq_off + cch], s2);
            atomicMax((unsigned*)meta + maxe_off + cch, fenc(m1));
            atomicMax((unsigned*)meta + maxneg_off + cch, fenc(m2));
        }
    }
}

// ---------------- BN finalize: scale/shift + analytic quant absmax ----------------
__global__ void bn_finalize_kernel(float* __restrict__ meta, int sum_off, int ssq_off,
                                   int maxe_off, int maxneg_off, int scale_off, int shift_off,
                                   int amax_slot,
                                   const float* __restrict__ gamma, const float* __restrict__ beta) {
    __shared__ float red[128];
    int c = threadIdx.x;   // 128 threads
    float mean = meta[sum_off + c] * (1.f / NHW);
    float var = meta[ssq_off + c] * (1.f / NHW) - mean * mean;
    float istd = rsqrtf(var + 1e-5f);
    float sc = gamma[c] * istd;
    float sh = beta[c] - mean * sc;
    meta[scale_off + c] = sc;
    meta[shift_off + c] = sh;
    if (amax_slot >= 0) {
        float vmax = fdec(((unsigned*)meta)[maxe_off + c]);
        float vmin = -fdec(((unsigned*)meta)[maxneg_off + c]);
        float cand = fmaxf(0.f, fmaxf(sc * vmax + sh, sc * vmin + sh));
        red[c] = cand;
        __syncthreads();
        for (int k = 64; k > 0; k >>= 1) {
            if (c < k) red[c] = fmaxf(red[c], red[c + k]);
            __syncthreads();
        }
        if (c == 0) meta[amax_slot] = red[0];
    }
}

// ---------------- BN+ReLU+quant: y1 (NHWC bf16) -> a2q (pre-swizzled i8 slabs) ----------------
__global__ void quant_bnrelu_kernel(const short* __restrict__ y1, const float* __restrict__ meta,
                                    char* __restrict__ a2q) {
    int h = blockIdx.x, n = blockIdx.y, t = threadIdx.x;
    const short* row = y1 + (((size_t)n * H + h) * W) * C;
    float qs = 127.f / (meta[SLOT_SA2] + 1e-12f);
    char* slab = a2q + ((size_t)n * HP + (h + 1)) * SLAB;
    #pragma unroll
    for (int i = 0; i < 2; ++i) {
        int g = i * 256 + t;
        if (g < 448) {                  // 56 w * 8 groups of 16 ch
            int w = g >> 3, cg = g & 7;
            bf16x8 v0 = *(const bf16x8*)(row + w * 128 + cg * 16);
            bf16x8 v1 = *(const bf16x8*)(row + w * 128 + cg * 16 + 8);
            union { char c[16]; i32x4 v; } u;
            #pragma unroll
            for (int j = 0; j < 8; ++j) {
                float a = fmaxf(bf2f(v0[j]) * meta[SCALE1 + cg * 16 + j] + meta[SHIFT1 + cg * 16 + j], 0.f);
                u.c[j] = (char)(int)rintf(a * qs);
            }
            #pragma unroll
            for (int j = 0; j < 8; ++j) {
                float a = fmaxf(bf2f(v1[j]) * meta[SCALE1 + cg * 16 + 8 + j] + meta[SHIFT1 + cg * 16 + 8 + j], 0.f);
                u.c[8 + j] = (char)(int)rintf(a * qs);
            }
            int wp = w + 1;
            int L = wp * 128 + cg * 16;
            *(i32x4*)(slab + (L ^ ((wp & 7) << 4))) = u.v;
        }
    }
}

// ---------------- final: out = relu(bn2(y2) + x), NHWC bf16 -> NCHW fp32 via LDS ----------------
__global__ void final_kernel(const short* __restrict__ y2, const float* __restrict__ x,
                             const float* __restrict__ meta, float* __restrict__ out) {
    __shared__ short tile[56 * 128];
    int h = blockIdx.x, n = blockIdx.y, t = threadIdx.x;
    const short* row = y2 + (((size_t)n * H + h) * W) * C;
    #pragma unroll
    for (int i = 0; i < 4; ++i) {
        int g = i * 256 + t;
        if (g < 896) *(bf16x8*)(tile + g * 8) = *(const bf16x8*)(row + g * 8);
    }
    __syncthreads();
    int c = t >> 1, seg = (t & 1) * 28;
    float sc = meta[SCALE2 + c], sh = meta[SHIFT2 + c];
    const float* xr = x + (((size_t)(n * C + c)) * H + h) * W + seg;
    float* orow = out + (((size_t)(n * C + c)) * H + h) * W + seg;
    #pragma unroll
    for (int j = 0; j < 28; j += 4) {
        f32x4 xv = *(const f32x4*)(xr + j);
        f32x4 o;
        #pragma unroll
        for (int k = 0; k < 4; ++k) {
            float yv = bf2f(tile[(seg + j + k) * 128 + c]);
            o[k] = fmaxf(yv * sc + sh + xv[k], 0.f);
        }
        *(f32x4*)(orow + j) = o;
    }
}

extern "C" void kernel_launch(void* const* d_in, const int* in_sizes, int n_in,
                              void* d_out, int out_size, void* d_ws, size_t ws_size,
                              hipStream_t stream) {
    const float* x      = (const float*)d_in[0];
    const float* w1     = (const float*)d_in[1];
    const float* gamma1 = (const float*)d_in[2];
    const float* beta1  = (const float*)d_in[3];
    const float* w2     = (const float*)d_in[4];
    const float* gamma2 = (const float*)d_in[5];
    const float* beta2  = (const float*)d_in[6];
    float* out = (float*)d_out;
    char* ws = (char*)d_ws;

    float* meta = (float*)(ws + META_OFF);
    unsigned* metau = (unsigned*)meta;
    char* xq   = ws + XQ_OFF;
    char* a2q  = ws + A2Q_OFF;
    short* y1  = (short*)(ws + Y1_OFF);
    short* y2  = (short*)(ws + Y2_OFF);
    char* w1q  = ws + W1Q_OFF;
    char* w2q  = ws + W2Q_OFF;

    hipMemsetAsync(ws + META_OFF, 0, META_BYTES, stream);
    pad_zero_kernel<<<dim3(59, 32, 2), 256, 0, stream>>>(xq, a2q);

    absmax_kernel<<<1024, 256, 0, stream>>>(x, ELTS / 4, metau + SLOT_SX);
    absmax_kernel<<<64, 256, 0, stream>>>(w1, 147456 / 4, metau + SLOT_SW1);
    absmax_kernel<<<64, 256, 0, stream>>>(w2, 147456 / 4, metau + SLOT_SW2);

    quant_w_kernel<<<64, 256, 0, stream>>>(w1, meta, SLOT_SW1, w1q);
    quant_w_kernel<<<64, 256, 0, stream>>>(w2, meta, SLOT_SW2, w2q);

    dim3 ghn(56, 32);
    quant_x_kernel<<<ghn, 256, 0, stream>>>(x, meta, xq);

    dim3 gconv(28, 32);
    conv_mfma_kernel<<<gconv, 256, 0, stream>>>(xq, w1q, y1, meta, SLOT_SX, SLOT_SW1,
                                                SUM1, SSQ1, MAXE1, MAXNEG1);
    bn_finalize_kernel<<<1, 128, 0, stream>>>(meta, SUM1, SSQ1, MAXE1, MAXNEG1,
                                              SCALE1, SHIFT1, SLOT_SA2, gamma1, beta1);
    quant_bnrelu_kernel<<<ghn, 256, 0, stream>>>(y1, meta, a2q);

    conv_mfma_kernel<<<gconv, 256, 0, stream>>>(a2q, w2q, y2, meta, SLOT_SA2, SLOT_SW2,
                                                SUM2, SSQ2, MAXE2, MAXNEG2);
    bn_finalize_kernel<<<1, 128, 0, stream>>>(meta, SUM2, SSQ2, MAXE2, MAXNEG2,
                                              SCALE2, SHIFT2, -1, gamma2, beta2);

    final_kernel<<<ghn, 256, 0, stream>>>(y2, x, meta, out);
}

// Round 4
// 251.325 us; speedup vs baseline: 2.2672x; 2.2672x over previous
//
#include <hip/hip_runtime.h>

// ---------------- problem constants ----------------
#define NB 32
#define C 128
#define H 56
#define W 56
#define HWSZ (H*W)                 // 3136
#define ELTS (NB*C*HWSZ)           // 12,845,056
#define NHW (NB*HWSZ)              // 100,352 per-channel count
#define HP 59                      // padded rows (h' = 0..58, data at 1..56)
#define SLAB 8192                  // bytes per (n,h') slab: 64 w' * 128 c * 1B (i8)
#define GCONVX 28                  // conv grid x (2 rows per block)
#define NBLK (GCONVX*NB)           // 896 conv blocks
#define PSTRIDE (C*NBLK)           // floats per stat plane: 114,688

typedef __attribute__((ext_vector_type(8))) short bf16x8;
typedef __attribute__((ext_vector_type(4))) short short4v;
typedef __attribute__((ext_vector_type(4))) float f32x4;
typedef __attribute__((ext_vector_type(4))) int i32x4;

// ---------------- meta (float offsets) ----------------
#define SLOT_SX 0
#define SLOT_SW1 1
#define SLOT_SW2 2
#define SLOT_SA2 3
#define SUM1 8
#define SSQ1 136
#define MAXE1 264
#define MAXNEG1 392
#define SCALE1 520
#define SHIFT1 648
#define SUM2 776
#define SSQ2 904
#define MAXE2 1032
#define MAXNEG2 1160
#define SCALE2 1288
#define SHIFT2 1416

// ---------------- workspace byte offsets ----------------
#define META_OFF 0ull
#define META_BYTES 8192ull
#define XQ_OFF 8192ull
#define XQ_BYTES ((unsigned long long)NB*HP*SLAB)      // 15,466,496
#define A2Q_OFF (XQ_OFF + XQ_BYTES)
#define Y1_OFF (A2Q_OFF + XQ_BYTES)
#define Y_BYTES ((unsigned long long)ELTS*2ull)        // 25,690,112 (bf16)
#define Y2_OFF (Y1_OFF + Y_BYTES)
#define W1Q_OFF (Y2_OFF + Y_BYTES)
#define WQ_BYTES (9ull*2*128*64)                       // 147,456 (i8, [tap][cc][co][64])
#define W2Q_OFF (W1Q_OFF + WQ_BYTES)
#define PART_OFF (W2Q_OFF + WQ_BYTES)
#define PART_BYTES (4ull*PSTRIDE*4ull)                 // 1,835,008
// total ~84.4 MB

__device__ __forceinline__ short f2bf_rne(float f) {       // round-nearest-even
    unsigned u = __float_as_uint(f);
    return (short)((u + 0x7FFFu + ((u >> 16) & 1u)) >> 16);
}
__device__ __forceinline__ float bf2f(short s) {
    return __uint_as_float(((unsigned)(unsigned short)s) << 16);
}

// ---------------- absmax reduction (values >= 0, bits-monotone atomicMax ok) ----------------
__global__ void absmax_kernel(const float* __restrict__ p, int n4, unsigned* __restrict__ slot) {
    __shared__ float red[256];
    float m = 0.f;
    int stride = gridDim.x * blockDim.x;
    for (int i = blockIdx.x * blockDim.x + threadIdx.x; i < n4; i += stride) {
        f32x4 v = ((const f32x4*)p)[i];
        m = fmaxf(m, fmaxf(fmaxf(fabsf(v.x), fabsf(v.y)), fmaxf(fabsf(v.z), fabsf(v.w))));
    }
    red[threadIdx.x] = m;
    __syncthreads();
    for (int s = 128; s > 0; s >>= 1) {
        if (threadIdx.x < s) red[threadIdx.x] = fmaxf(red[threadIdx.x], red[threadIdx.x + s]);
        __syncthreads();
    }
    if (threadIdx.x == 0) atomicMax(slot, __float_as_uint(red[0]));
}

// ---------------- zero the pad regions of xq/a2q (ws re-poisoned each run) ----------------
__global__ void pad_zero_kernel(char* __restrict__ xq, char* __restrict__ a2q) {
    int hp = blockIdx.x;                 // 0..58
    int n = blockIdx.y;                  // 0..31
    char* base = (blockIdx.z ? a2q : xq) + ((size_t)n * HP + hp) * SLAB;
    int t = threadIdx.x;
    if (hp == 0 || hp >= 57) {           // full pad rows: 8192B
        f32x4 z = {0.f, 0.f, 0.f, 0.f};
        *(f32x4*)(base + t * 16) = z;
        *(f32x4*)(base + 4096 + t * 16) = z;
    } else {                             // column pads: w'=0 (128B) and w'=57..63 (896B)
        if (t < 32) *(int*)(base + t * 4) = 0;
        else        *(int*)(base + 7296 + (t - 32) * 4) = 0;
    }
}

// ---------------- weight quant + layout [tap][cc][co][64] i8 ----------------
__global__ void quant_w_kernel(const float* __restrict__ w, const float* __restrict__ meta,
                               int slot, char* __restrict__ wq) {
    int idx = blockIdx.x * 256 + threadIdx.x;   // 0..16383
    int co = idx >> 7, ci = idx & 127;
    float qs = 127.f / (meta[slot] + 1e-12f);
    const float* src = w + ((size_t)(co * 128 + ci)) * 9;
    int cc = ci >> 6, cl = ci & 63;
    #pragma unroll
    for (int tap = 0; tap < 9; ++tap) {
        int q = (int)rintf(src[tap] * qs);
        wq[(((size_t)tap * 2 + cc) * 128 + co) * 64 + cl] = (char)q;
    }
}

// ---------------- quantize x (NCHW fp32) -> pre-swizzled padded NHWC i8 codes ----------------
__global__ void quant_x_kernel(const float* __restrict__ x, const float* __restrict__ meta,
                               char* __restrict__ xq) {
    __shared__ float tile[128][57];
    int h = blockIdx.x, n = blockIdx.y, t = threadIdx.x;
    int ci = t >> 1, seg = (t & 1) * 28;
    const float* row = x + (((size_t)(n * C + ci)) * H + h) * W + seg;
    #pragma unroll
    for (int j = 0; j < 28; j += 4) {
        f32x4 v = *(const f32x4*)(row + j);
        tile[ci][seg + j + 0] = v.x;
        tile[ci][seg + j + 1] = v.y;
        tile[ci][seg + j + 2] = v.z;
        tile[ci][seg + j + 3] = v.w;
    }
    __syncthreads();
    float qs = 127.f / (meta[SLOT_SX] + 1e-12f);
    int w = t & 63, cq = t >> 6;        // cq: 32-channel group
    if (w < 56) {
        char* slab = xq + ((size_t)n * HP + (h + 1)) * SLAB;
        int wp = w + 1;
        #pragma unroll
        for (int c2 = 0; c2 < 2; ++c2) {
            union { char c[16]; i32x4 v; } u;
            #pragma unroll
            for (int j = 0; j < 16; ++j)
                u.c[j] = (char)(int)rintf(tile[cq * 32 + c2 * 16 + j][w] * qs);
            int L = wp * 128 + cq * 32 + c2 * 16;
            *(i32x4*)(slab + (L ^ ((wp & 7) << 4))) = u.v;
        }
    }
}

// ---------------- conv 3x3 implicit-GEMM i8 MFMA, 2 rows/block, tap-major ----------------
// xq: pre-swizzled padded i8 slabs; wq: [tap][cc][co][64]; y: NHWC bf16 (real units)
// Fused stats: per-channel sum/sumsq/max(v)/max(-v) -> PLAIN per-block partial stores (no atomics).
__global__ __launch_bounds__(256, 4) void conv_mfma_kernel(
        const char* __restrict__ xq, const char* __restrict__ wq,
        short* __restrict__ y, const float* __restrict__ meta,
        float* __restrict__ part, int slot_in, int slot_w) {
    __shared__ __align__(16) char lds[4 * SLAB + 512];   // 4 slabs + OOB slack (wpp<=65)
    const int n = blockIdx.y, h0 = blockIdx.x * 2;       // output rows h0, h0+1
    const int t = threadIdx.x, lane = t & 63;
    const int co0 = (t >> 6) * 32, l15 = lane & 15, lg = lane >> 4;

    // stage padded input rows h0 .. h0+3 (slots 0..3), 2 x 16B loads per slab per thread
    const char* slabbase = xq + ((size_t)n * HP + h0) * SLAB;
    #pragma unroll
    for (int s = 0; s < 4; ++s) {
        #pragma unroll
        for (int i = 0; i < 2; ++i) {
            int off = (i * 256 + t) * 16;
            __builtin_amdgcn_global_load_lds(
                (const __attribute__((address_space(1))) unsigned*)(slabbase + s * SLAB + off),
                (__attribute__((address_space(3))) unsigned*)(lds + s * SLAB + off), 16, 0, 0);
        }
    }

    i32x4 acc[2][4][2] = {};   // [row][fj][cohalf]

    #pragma unroll
    for (int kh = 0; kh < 3; ++kh) {
        if (kh == 0)      { asm volatile("s_waitcnt vmcnt(4)" ::: "memory"); }
        else if (kh == 1) { asm volatile("s_waitcnt vmcnt(2)" ::: "memory"); }
        else              { asm volatile("s_waitcnt vmcnt(0)" ::: "memory"); }
        __builtin_amdgcn_s_barrier();
        #pragma unroll
        for (int kw = 0; kw < 3; ++kw) {
            #pragma unroll
            for (int cc = 0; cc < 2; ++cc) {
                const char* wt = wq + (((kh * 3 + kw) * 2 + cc) << 13);
                i32x4 a0 = *(const i32x4*)(wt + (co0 + l15) * 64 + lg * 16);
                i32x4 a1 = *(const i32x4*)(wt + (co0 + 16 + l15) * 64 + lg * 16);
                #pragma unroll
                for (int r = 0; r < 2; ++r) {
                    const char* Bb = lds + (kh + r) * SLAB;
                    #pragma unroll
                    for (int fj = 0; fj < 4; ++fj) {
                        int wpp = fj * 16 + l15 + kw;
                        int L = (wpp << 7) + (cc << 6) + (lg << 4);
                        i32x4 b = *(const i32x4*)(Bb + (L ^ ((wpp & 7) << 4)));
                        acc[r][fj][0] = __builtin_amdgcn_mfma_i32_16x16x64_i8(a0, b, acc[r][fj][0], 0, 0, 0);
                        acc[r][fj][1] = __builtin_amdgcn_mfma_i32_16x16x64_i8(a1, b, acc[r][fj][1], 0, 0, 0);
                    }
                }
            }
        }
    }

    // epilogue: dequant, stats, bf16 NHWC store
    float dq = (meta[slot_in] + 1e-12f) * (meta[slot_w] + 1e-12f) * (1.f / 16129.f);

    float a_sum[8] = {}, a_ssq[8] = {}, a_mx[8], a_mxn[8];
    #pragma unroll
    for (int i = 0; i < 8; ++i) { a_mx[i] = -1e30f; a_mxn[i] = -1e30f; }

    #pragma unroll
    for (int r = 0; r < 2; ++r) {
        short* yrow = y + (((size_t)n * H + (h0 + r)) * W) * C;
        #pragma unroll
        for (int ai = 0; ai < 2; ++ai) {
            #pragma unroll
            for (int fj = 0; fj < 4; ++fj) {
                int wo = fj * 16 + l15;
                if (wo < W) {
                    short4v pk;
                    #pragma unroll
                    for (int q = 0; q < 4; ++q) {
                        float v = (float)acc[r][fj][ai][q] * dq;
                        int si = ai * 4 + q;
                        a_sum[si] += v;
                        a_ssq[si] += v * v;
                        a_mx[si]  = fmaxf(a_mx[si], v);
                        a_mxn[si] = fmaxf(a_mxn[si], -v);
                        pk[q] = f2bf_rne(v);
                    }
                    *(short4v*)(yrow + (size_t)wo * C + co0 + ai * 16 + lg * 4) = pk;
                }
            }
        }
    }

    // cross-l15 reduce (16 lanes share a channel set), then plain per-block partial stores
    int bid = blockIdx.y * GCONVX + blockIdx.x;
    #pragma unroll
    for (int si = 0; si < 8; ++si) {
        float s1 = a_sum[si], s2 = a_ssq[si], m1 = a_mx[si], m2 = a_mxn[si];
        #pragma unroll
        for (int m = 1; m < 16; m <<= 1) {
            s1 += __shfl_xor(s1, m, 64);
            s2 += __shfl_xor(s2, m, 64);
            m1 = fmaxf(m1, __shfl_xor(m1, m, 64));
            m2 = fmaxf(m2, __shfl_xor(m2, m, 64));
        }
        if (l15 == 0) {
            int cch = co0 + (si >> 2) * 16 + lg * 4 + (si & 3);
            part[0 * PSTRIDE + cch * NBLK + bid] = s1;
            part[1 * PSTRIDE + cch * NBLK + bid] = s2;
            part[2 * PSTRIDE + cch * NBLK + bid] = m1;
            part[3 * PSTRIDE + cch * NBLK + bid] = m2;
        }
    }
}

// ---------------- reduce per-block partials -> meta stats (one block per channel) ----------------
__global__ void bn_reduce_kernel(const float* __restrict__ part, float* __restrict__ meta,
                                 int sum_off, int ssq_off, int maxe_off, int maxneg_off) {
    __shared__ float r1[256], r2[256], r3[256], r4[256];
    int c = blockIdx.x, t = threadIdx.x;
    const float* ps = part + 0 * PSTRIDE + (size_t)c * NBLK;
    const float* pq = part + 1 * PSTRIDE + (size_t)c * NBLK;
    const float* pm = part + 2 * PSTRIDE + (size_t)c * NBLK;
    const float* pn = part + 3 * PSTRIDE + (size_t)c * NBLK;
    float s1 = 0.f, s2 = 0.f, m1 = -1e30f, m2 = -1e30f;
    for (int i = t; i < NBLK; i += 256) {
        s1 += ps[i];
        s2 += pq[i];
        m1 = fmaxf(m1, pm[i]);
        m2 = fmaxf(m2, pn[i]);
    }
    r1[t] = s1; r2[t] = s2; r3[t] = m1; r4[t] = m2;
    __syncthreads();
    for (int k = 128; k > 0; k >>= 1) {
        if (t < k) {
            r1[t] += r1[t + k];
            r2[t] += r2[t + k];
            r3[t] = fmaxf(r3[t], r3[t + k]);
            r4[t] = fmaxf(r4[t], r4[t + k]);
        }
        __syncthreads();
    }
    if (t == 0) {
        meta[sum_off + c] = r1[0];
        meta[ssq_off + c] = r2[0];
        meta[maxe_off + c] = r3[0];
        meta[maxneg_off + c] = r4[0];
    }
}

// ---------------- BN finalize: scale/shift + analytic quant absmax ----------------
__global__ void bn_finalize_kernel(float* __restrict__ meta, int sum_off, int ssq_off,
                                   int maxe_off, int maxneg_off, int scale_off, int shift_off,
                                   int amax_slot,
                                   const float* __restrict__ gamma, const float* __restrict__ beta) {
    __shared__ float red[128];
    int c = threadIdx.x;   // 128 threads
    float mean = meta[sum_off + c] * (1.f / NHW);
    float var = meta[ssq_off + c] * (1.f / NHW) - mean * mean;
    float istd = rsqrtf(var + 1e-5f);
    float sc = gamma[c] * istd;
    float sh = beta[c] - mean * sc;
    meta[scale_off + c] = sc;
    meta[shift_off + c] = sh;
    if (amax_slot >= 0) {
        float vmax = meta[maxe_off + c];
        float vmin = -meta[maxneg_off + c];
        float cand = fmaxf(0.f, fmaxf(sc * vmax + sh, sc * vmin + sh));
        red[c] = cand;
        __syncthreads();
        for (int k = 64; k > 0; k >>= 1) {
            if (c < k) red[c] = fmaxf(red[c], red[c + k]);
            __syncthreads();
        }
        if (c == 0) meta[amax_slot] = red[0];
    }
}

// ---------------- BN+ReLU+quant: y1 (NHWC bf16) -> a2q (pre-swizzled i8 slabs) ----------------
__global__ void quant_bnrelu_kernel(const short* __restrict__ y1, const float* __restrict__ meta,
                                    char* __restrict__ a2q) {
    int h = blockIdx.x, n = blockIdx.y, t = threadIdx.x;
    const short* row = y1 + (((size_t)n * H + h) * W) * C;
    float qs = 127.f / (meta[SLOT_SA2] + 1e-12f);
    char* slab = a2q + ((size_t)n * HP + (h + 1)) * SLAB;
    #pragma unroll
    for (int i = 0; i < 2; ++i) {
        int g = i * 256 + t;
        if (g < 448) {                  // 56 w * 8 groups of 16 ch
            int w = g >> 3, cg = g & 7;
            bf16x8 v0 = *(const bf16x8*)(row + w * 128 + cg * 16);
            bf16x8 v1 = *(const bf16x8*)(row + w * 128 + cg * 16 + 8);
            union { char c[16]; i32x4 v; } u;
            #pragma unroll
            for (int j = 0; j < 8; ++j) {
                float a = fmaxf(bf2f(v0[j]) * meta[SCALE1 + cg * 16 + j] + meta[SHIFT1 + cg * 16 + j], 0.f);
                u.c[j] = (char)(int)rintf(a * qs);
            }
            #pragma unroll
            for (int j = 0; j < 8; ++j) {
                float a = fmaxf(bf2f(v1[j]) * meta[SCALE1 + cg * 16 + 8 + j] + meta[SHIFT1 + cg * 16 + 8 + j], 0.f);
                u.c[8 + j] = (char)(int)rintf(a * qs);
            }
            int wp = w + 1;
            int L = wp * 128 + cg * 16;
            *(i32x4*)(slab + (L ^ ((wp & 7) << 4))) = u.v;
        }
    }
}

// ---------------- final: out = relu(bn2(y2) + x), NHWC bf16 -> NCHW fp32 via LDS ----------------
__global__ void final_kernel(const short* __restrict__ y2, const float* __restrict__ x,
                             const float* __restrict__ meta, float* __restrict__ out) {
    __shared__ short tile[56 * 128];
    int h = blockIdx.x, n = blockIdx.y, t = threadIdx.x;
    const short* row = y2 + (((size_t)n * H + h) * W) * C;
    #pragma unroll
    for (int i = 0; i < 4; ++i) {
        int g = i * 256 + t;
        if (g < 896) *(bf16x8*)(tile + g * 8) = *(const bf16x8*)(row + g * 8);
    }
    __syncthreads();
    int c = t >> 1, seg = (t & 1) * 28;
    float sc = meta[SCALE2 + c], sh = meta[SHIFT2 + c];
    const float* xr = x + (((size_t)(n * C + c)) * H + h) * W + seg;
    float* orow = out + (((size_t)(n * C + c)) * H + h) * W + seg;
    #pragma unroll
    for (int j = 0; j < 28; j += 4) {
        f32x4 xv = *(const f32x4*)(xr + j);
        f32x4 o;
        #pragma unroll
        for (int k = 0; k < 4; ++k) {
            float yv = bf2f(tile[(seg + j + k) * 128 + c]);
            o[k] = fmaxf(yv * sc + sh + xv[k], 0.f);
        }
        *(f32x4*)(orow + j) = o;
    }
}

extern "C" void kernel_launch(void* const* d_in, const int* in_sizes, int n_in,
                              void* d_out, int out_size, void* d_ws, size_t ws_size,
                              hipStream_t stream) {
    const float* x      = (const float*)d_in[0];
    const float* w1     = (const float*)d_in[1];
    const float* gamma1 = (const float*)d_in[2];
    const float* beta1  = (const float*)d_in[3];
    const float* w2     = (const float*)d_in[4];
    const float* gamma2 = (const float*)d_in[5];
    const float* beta2  = (const float*)d_in[6];
    float* out = (float*)d_out;
    char* ws = (char*)d_ws;

    float* meta = (float*)(ws + META_OFF);
    unsigned* metau = (unsigned*)meta;
    char* xq   = ws + XQ_OFF;
    char* a2q  = ws + A2Q_OFF;
    short* y1  = (short*)(ws + Y1_OFF);
    short* y2  = (short*)(ws + Y2_OFF);
    char* w1q  = ws + W1Q_OFF;
    char* w2q  = ws + W2Q_OFF;
    float* part = (float*)(ws + PART_OFF);

    hipMemsetAsync(ws + META_OFF, 0, META_BYTES, stream);
    pad_zero_kernel<<<dim3(59, 32, 2), 256, 0, stream>>>(xq, a2q);

    absmax_kernel<<<1024, 256, 0, stream>>>(x, ELTS / 4, metau + SLOT_SX);
    absmax_kernel<<<64, 256, 0, stream>>>(w1, 147456 / 4, metau + SLOT_SW1);
    absmax_kernel<<<64, 256, 0, stream>>>(w2, 147456 / 4, metau + SLOT_SW2);

    quant_w_kernel<<<64, 256, 0, stream>>>(w1, meta, SLOT_SW1, w1q);
    quant_w_kernel<<<64, 256, 0, stream>>>(w2, meta, SLOT_SW2, w2q);

    dim3 ghn(56, 32);
    quant_x_kernel<<<ghn, 256, 0, stream>>>(x, meta, xq);

    dim3 gconv(GCONVX, 32);
    conv_mfma_kernel<<<gconv, 256, 0, stream>>>(xq, w1q, y1, meta, part, SLOT_SX, SLOT_SW1);
    bn_reduce_kernel<<<128, 256, 0, stream>>>(part, meta, SUM1, SSQ1, MAXE1, MAXNEG1);
    bn_finalize_kernel<<<1, 128, 0, stream>>>(meta, SUM1, SSQ1, MAXE1, MAXNEG1,
                                              SCALE1, SHIFT1, SLOT_SA2, gamma1, beta1);
    quant_bnrelu_kernel<<<ghn, 256, 0, stream>>>(y1, meta, a2q);

    conv_mfma_kernel<<<gconv, 256, 0, stream>>>(a2q, w2q, y2, meta, part, SLOT_SA2, SLOT_SW2);
    bn_reduce_kernel<<<128, 256, 0, stream>>>(part, meta, SUM2, SSQ2, MAXE2, MAXNEG2);
    bn_finalize_kernel<<<1, 128, 0, stream>>>(meta, SUM2, SSQ2, MAXE2, MAXNEG2,
                                              SCALE2, SHIFT2, -1, gamma2, beta2);

    final_kernel<<<ghn, 256, 0, stream>>>(y2, x, meta, out);
}